// Round 10
// baseline (166.504 us; speedup 1.0000x reference)
//
#include <hip/hip_runtime.h>
#include <math.h>
#include <stdint.h>

#define NPROJ 16
#define NBINS 65536
#define WD (NBINS - 6)
#define BMW 2056              // bitmap u32 words per bp (8224 B); bit k = old byte k
#define B_ 2
#define C_ 3
#define H_ 384
#define W_ 384
#define HO 378
#define NPAT (HO * HO)        // 142884 (div by 4)
#define DF 147                // 3*7*7
#define BP 32                 // B_*NPROJ
#define TSTR 24               // LDS tile row stride -> uniform 2-way (free)

__device__ inline unsigned f2key(float f) {
    unsigned u = __float_as_uint(f);
    return (u & 0x80000000u) ? ~u : (u | 0x80000000u);
}
__device__ inline float key2f(unsigned k) {
    unsigned u = (k & 0x80000000u) ? (k ^ 0x80000000u) : ~k;
    return __uint_as_float(u);
}

// packed dual-FMA: acc.{x,y} += pix.{x,y} * w.x   (w broadcast from SGPR-pair lo)
__device__ inline void pkfma_lo(float2& acc, float2 pix, float2 w) {
    asm("v_pk_fma_f32 %0, %1, %2, %0 op_sel:[0,0,0] op_sel_hi:[1,0,1]"
        : "+v"(acc) : "v"(pix), "s"(w));
}
// acc.{x,y} += pix.{x,y} * w.y   (broadcast hi half)
__device__ inline void pkfma_hi(float2& acc, float2 pix, float2 w) {
    asm("v_pk_fma_f32 %0, %1, %2, %0 op_sel:[0,1,0] op_sel_hi:[1,1,1]"
        : "+v"(acc) : "v"(pix), "s"(w));
}

// ---------- K0: rand/std (ddof=1); init keys; zero out -----------------------
__global__ __launch_bounds__(64) void k_rnorm(const float* __restrict__ rnd,
                                              float* __restrict__ rnorm,
                                              unsigned* __restrict__ keys,
                                              float* __restrict__ out) {
    int bp = blockIdx.x;
    int b = bp / NPROJ, p = bp % NPROJ;
    int lane = threadIdx.x;
    if (lane == 0) {
        keys[2 * bp] = 0xFFFFFFFFu;
        keys[2 * bp + 1] = 0u;
        if (bp == 0) out[0] = 0.f;     // accumulated atomically in k_gather
    }
    float s = 0.f, s2 = 0.f;
    for (int d = lane; d < DF; d += 64) {
        float v = rnd[((size_t)b * DF + d) * NPROJ + p];
        s += v; s2 += v * v;
    }
    for (int o = 32; o > 0; o >>= 1) { s += __shfl_down(s, o); s2 += __shfl_down(s2, o); }
    s = __shfl(s, 0); s2 = __shfl(s2, 0);
    float mean = s / (float)DF;
    float var = (s2 - (float)DF * mean * mean) / (float)(DF - 1);
    float inv = 1.0f / sqrtf(var);
    for (int d = lane; d < DF; d += 64) {
        size_t idx = ((size_t)b * DF + d) * NPROJ + p;
        rnorm[idx] = rnd[idx] * inv;
    }
}

// ---------- K1: proj both images; store px AND py; min/max atomics -----------
// tile 32(h)x16(w), 256 threads, 2 outputs/thread packed into float2 accs.
// grid (24,12,4): z=b*2+isy. Weights via wave-uniform s_load (SGPR pairs).
#define T1H 32
#define T1W 16
__global__ __launch_bounds__(256) void k_projmm(const float* __restrict__ ximg,
                                                const float* __restrict__ yimg,
                                                const float* __restrict__ rnorm,
                                                float* __restrict__ px,
                                                float* __restrict__ py,
                                                unsigned* __restrict__ keys) {
    __shared__ float tile[C_][T1H + 6][TSTR];   // [3][38][24]
    __shared__ float red_mn[4][NPROJ], red_mx[4][NPROJ];
    int bz = blockIdx.z;
    int b = bz >> 1, isy = bz & 1;
    const float* img = isy ? yimg : ximg;
    float* proj = isy ? py : px;
    int tid = threadIdx.x;
    int tx = tid & 15, ty = tid >> 4;              // 16x16 threads, rows 16 apart
    int h0 = blockIdx.y * T1H, w0 = blockIdx.x * T1W;

    for (int c = 0; c < C_; c++)
        for (int i = tid; i < (T1H + 6) * (T1W + 6); i += 256) {
            int r = i / (T1W + 6), col = i % (T1W + 6);
            int h = h0 + r, w = w0 + col;
            tile[c][r][col] = (h < H_ && w < W_)
                ? img[((size_t)(b * C_ + c) * H_ + h) * W_ + w] : 0.f;
        }
    __syncthreads();

    const float* wbase = rnorm + (size_t)b * DF * NPROJ;

    float2 accv[NPROJ];                 // .x = row ty, .y = row ty+16
#pragma unroll
    for (int p = 0; p < NPROJ; p++) accv[p] = make_float2(0.f, 0.f);

    for (int c = 0; c < C_; c++)
        for (int i = 0; i < 7; i++)
#pragma unroll
            for (int j = 0; j < 7; j++) {
                const float2* wrow2 =
                    (const float2*)(wbase + (c * 49 + i * 7 + j) * NPROJ); // uniform
                float2 pp = make_float2(tile[c][ty + i][tx + j],
                                        tile[c][ty + 16 + i][tx + j]);
#pragma unroll
                for (int q = 0; q < 8; q++) {
                    float2 w2 = wrow2[q];        // SGPR pair via s_load
                    pkfma_lo(accv[2 * q], pp, w2);
                    pkfma_hi(accv[2 * q + 1], pp, w2);
                }
            }

    int wo = w0 + tx;
    int ho0 = h0 + ty, ho1 = h0 + ty + 16;
    bool vm0 = (ho0 < HO) && (wo < HO);
    bool vm1 = (ho1 < HO) && (wo < HO);

    if (vm0) {
        size_t n = (size_t)ho0 * HO + wo;
#pragma unroll
        for (int p = 0; p < NPROJ; p++)
            proj[((size_t)(b * NPROJ + p)) * NPAT + n] = accv[p].x;
    }
    if (vm1) {
        size_t n = (size_t)ho1 * HO + wo;
#pragma unroll
        for (int p = 0; p < NPROJ; p++)
            proj[((size_t)(b * NPROJ + p)) * NPAT + n] = accv[p].y;
    }

    float pmn[NPROJ], pmx[NPROJ];
#pragma unroll
    for (int p = 0; p < NPROJ; p++) {
        float mn = INFINITY, mx = -INFINITY;
        if (vm0) { mn = accv[p].x; mx = accv[p].x; }
        if (vm1) { mn = fminf(mn, accv[p].y); mx = fmaxf(mx, accv[p].y); }
        pmn[p] = mn; pmx[p] = mx;
    }
#pragma unroll
    for (int o = 1; o < 64; o <<= 1) {
#pragma unroll
        for (int p = 0; p < NPROJ; p++) {
            pmn[p] = fminf(pmn[p], __shfl_xor(pmn[p], o));
            pmx[p] = fmaxf(pmx[p], __shfl_xor(pmx[p], o));
        }
    }
    int wv4 = tid >> 6;
    if ((tid & 63) == 0) {
#pragma unroll
        for (int p = 0; p < NPROJ; p++) { red_mn[wv4][p] = pmn[p]; red_mx[wv4][p] = pmx[p]; }
    }
    __syncthreads();
    if (tid < NPROJ) {
        float mn = fminf(fminf(red_mn[0][tid], red_mn[1][tid]),
                         fminf(red_mn[2][tid], red_mn[3][tid]));
        float mx = fmaxf(fmaxf(red_mx[0][tid], red_mx[1][tid]),
                         fmaxf(red_mx[2][tid], red_mx[3][tid]));
        atomicMin(&keys[2 * (b * NPROJ + tid)], f2key(mn));
        atomicMax(&keys[2 * (b * NPROJ + tid) + 1], f2key(mx));
    }
}

// ---------- K2: y-hist scatter -> LDS bitmap, one atomicOr flush -------------
__global__ __launch_bounds__(256) void k_scatter(const float* __restrict__ py,
                                                 const unsigned* __restrict__ keys,
                                                 unsigned* __restrict__ bitmap) {
    __shared__ unsigned lbm[BMW];
    int bp = blockIdx.y;
    int tid = threadIdx.x;
    for (int i = tid; i < BMW; i += 256) lbm[i] = 0u;
    __syncthreads();

    float mn = key2f(keys[2 * bp]);
    float sc = key2f(keys[2 * bp + 1]) - mn;
    const float4* src = (const float4*)(py + (size_t)bp * NPAT);
    const int n4 = NPAT / 4;
    for (int i = blockIdx.x * blockDim.x + tid; i < n4;
         i += gridDim.x * blockDim.x) {
        float4 v = src[i];
        float vv[4] = { v.x, v.y, v.z, v.w };
#pragma unroll
        for (int j = 0; j < 4; j++) {
            int idx = (int)floorf(65535.f * (vv[j] - mn) / sc);
            int bit = 8 + min(max(idx, 0), 65535);
            atomicOr(&lbm[bit >> 5], 1u << (bit & 31));
        }
    }
    __syncthreads();
    unsigned* dst = bitmap + (size_t)bp * BMW;
    for (int i = tid; i < BMW; i += 256) {
        unsigned w = lbm[i];
        if (w) atomicOr(&dst[i], w);
    }
}

// ---------- K3: gather via LDS-staged bitmap + 256-entry LDS LUT -------------
__global__ __launch_bounds__(256) void k_gather(const float* __restrict__ px,
                                                const unsigned* __restrict__ keys,
                                                const unsigned* __restrict__ bitmap,
                                                float* __restrict__ out) {
    __shared__ unsigned lbm[BMW];
    __shared__ float2 lut[256];
    __shared__ float sred[4];
    int bp = blockIdx.y;
    int tid = threadIdx.x;

    const unsigned* gbm = bitmap + (size_t)bp * BMW;
    for (int i = tid; i < BMW; i += 256) lbm[i] = gbm[i];

    float g[7];
#pragma unroll
    for (int k = 0; k < 7; k++) {
        float d = (float)(k - 3);
        g[k] = expf(-(d * d) / 1.44f);   // exp((x)^2/(-2*1.2^2))**2
    }
    {
        int m = tid;   // 256 threads -> one LUT entry each
        float f[8];
#pragma unroll
        for (int k = 0; k < 8; k++) f[k] = (float)((m >> k) & 1);
        float s0 = g[0] * f[0] + g[1] * f[1] + g[2] * f[2] + g[3] * f[3]
                 + g[4] * f[4] + g[5] * f[5] + g[6] * f[6];
        float s1 = g[0] * f[1] + g[1] * f[2] + g[2] * f[3] + g[3] * f[4]
                 + g[4] * f[5] + g[5] * f[6] + g[6] * f[7];
        lut[m] = make_float2(fminf(s0, 1.f), fminf(s1, 1.f));
    }
    __syncthreads();

    float mn = key2f(keys[2 * bp]);
    float sc = key2f(keys[2 * bp + 1]) - mn;
    const float4* src = (const float4*)(px + (size_t)bp * NPAT);

    float acc = 0.f;
    const int n4 = NPAT / 4;
    for (int i = blockIdx.x * blockDim.x + tid; i < n4;
         i += gridDim.x * blockDim.x) {
        float4 v4 = src[i];
        float vv[4] = { v4.x, v4.y, v4.z, v4.w };
#pragma unroll
        for (int j = 0; j < 4; j++) {
            float v = vv[j];
            float t = (v - mn) / sc;             // in [0,1]
            float ix = t * (float)WD - 0.5f;
            float x0 = floorf(ix);
            float w1 = ix - x0;
            int x0i = (int)x0;                   // [-1, WD-1]
            int bit0 = 8 + x0i;                  // [7, 65536]
            int w = bit0 >> 5, s = bit0 & 31;
            uint64_t d = (uint64_t)lbm[w] | ((uint64_t)lbm[w + 1] << 32);
            uint32_t w8 = (uint32_t)(d >> s) & 0xFFu;
            float2 sv = lut[w8];
            float r0 = (x0i >= 0) ? sv.x : 0.f;
            float r1 = (x0i + 1 < WD) ? sv.y : 0.f;
            acc += r0 * (1.f - w1) + r1 * w1;
        }
    }
    for (int o = 32; o > 0; o >>= 1) acc += __shfl_down(acc, o);
    int wv4 = tid >> 6;
    if ((tid & 63) == 0) sred[wv4] = acc;
    __syncthreads();
    if (tid == 0) {
        float t = sred[0] + sred[1] + sred[2] + sred[3];
        atomicAdd(out, -t * (1.0f / 32.0f));
    }
}

extern "C" void kernel_launch(void* const* d_in, const int* in_sizes, int n_in,
                              void* d_out, int out_size, void* d_ws, size_t ws_size,
                              hipStream_t stream) {
    (void)in_sizes; (void)n_in; (void)out_size; (void)ws_size;
    const float* x = (const float*)d_in[0];
    const float* y = (const float*)d_in[1];
    const float* rnd = (const float*)d_in[2];
    float* out = (float*)d_out;

    float* ws = (float*)d_ws;
    float* rnorm = ws;                                     // 4704 floats
    float* px = rnorm + (size_t)B_ * DF * NPROJ;           // BP*NPAT floats
    float* py = px + (size_t)BP * NPAT;                    // BP*NPAT floats
    unsigned* keys = (unsigned*)(py + (size_t)BP * NPAT);  // 2*BP
    unsigned* bitmap = keys + 2 * BP;                      // BP*BMW u32 (263 KB)

    k_rnorm<<<BP, 64, 0, stream>>>(rnd, rnorm, keys, out);
    hipMemsetAsync(bitmap, 0, (size_t)BP * BMW * sizeof(unsigned), stream);

    dim3 g1(384 / T1W, 384 / T1H, 2 * B_);                 // (24,12,4)
    k_projmm<<<g1, 256, 0, stream>>>(x, y, rnorm, px, py, keys);

    k_scatter<<<dim3(8, BP), 256, 0, stream>>>(py, keys, bitmap);
    k_gather<<<dim3(70, BP), 256, 0, stream>>>(px, keys, bitmap, out);
}

// Round 11
// 115.984 us; speedup vs baseline: 1.4356x; 1.4356x over previous
//
#include <hip/hip_runtime.h>
#include <math.h>
#include <stdint.h>

#define NPROJ 16
#define NBINS 65536
#define WD (NBINS - 6)
#define BMW 2056              // bitmap u32 words per bp (8224 B); bit k = old byte k
#define B_ 2
#define C_ 3
#define H_ 384
#define W_ 384
#define HO 378
#define NPAT (HO * HO)        // 142884 (div by 4)
#define DF 147                // 3*7*7
#define BP 32                 // B_*NPROJ

__device__ inline unsigned f2key(float f) {
    unsigned u = __float_as_uint(f);
    return (u & 0x80000000u) ? ~u : (u | 0x80000000u);
}
__device__ inline float key2f(unsigned k) {
    unsigned u = (k & 0x80000000u) ? (k ^ 0x80000000u) : ~k;
    return __uint_as_float(u);
}

// ---------- K0: rand/std (ddof=1); init keys; zero out -----------------------
__global__ __launch_bounds__(64) void k_rnorm(const float* __restrict__ rnd,
                                              float* __restrict__ rnorm,
                                              unsigned* __restrict__ keys,
                                              float* __restrict__ out) {
    int bp = blockIdx.x;
    int b = bp / NPROJ, p = bp % NPROJ;
    int lane = threadIdx.x;
    if (lane == 0) {
        keys[2 * bp] = 0xFFFFFFFFu;
        keys[2 * bp + 1] = 0u;
        if (bp == 0) out[0] = 0.f;     // accumulated atomically in k_gather
    }
    float s = 0.f, s2 = 0.f;
    for (int d = lane; d < DF; d += 64) {
        float v = rnd[((size_t)b * DF + d) * NPROJ + p];
        s += v; s2 += v * v;
    }
    for (int o = 32; o > 0; o >>= 1) { s += __shfl_down(s, o); s2 += __shfl_down(s2, o); }
    s = __shfl(s, 0); s2 = __shfl(s2, 0);
    float mean = s / (float)DF;
    float var = (s2 - (float)DF * mean * mean) / (float)(DF - 1);
    float inv = 1.0f / sqrtf(var);
    for (int d = lane; d < DF; d += 64) {
        size_t idx = ((size_t)b * DF + d) * NPROJ + p;
        rnorm[idx] = rnd[idx] * inv;
    }
}

// ---------- K1: proj both images; store px AND py; min/max atomics -----------
// tile 32x32, 256 threads, 4 outputs/thread (rows ty+8q). grid (12,12,4):
// z=b*2+isy. Weights via wave-uniform s_load (SGPR broadcast operands).
#define T1 32
#define TSTR2 40              // 38-wide rows, stride 40: 2-way bank alias (free)
__global__ __launch_bounds__(256) void k_projmm(const float* __restrict__ ximg,
                                                const float* __restrict__ yimg,
                                                const float* __restrict__ rnorm,
                                                float* __restrict__ px,
                                                float* __restrict__ py,
                                                unsigned* __restrict__ keys) {
    __shared__ float tile[C_][T1 + 6][TSTR2];   // [3][38][40] = 18240 B
    __shared__ float red_mn[4][NPROJ], red_mx[4][NPROJ];
    int bz = blockIdx.z;
    int b = bz >> 1, isy = bz & 1;
    const float* img = isy ? yimg : ximg;
    float* proj = isy ? py : px;
    int tid = threadIdx.x;
    int tx = tid & 31, ty = tid >> 5;              // 32x8 threads, 4 rows each (+8)
    int h0 = blockIdx.y * T1, w0 = blockIdx.x * T1;

    for (int c = 0; c < C_; c++)
        for (int i = tid; i < (T1 + 6) * (T1 + 6); i += 256) {
            int r = i / (T1 + 6), col = i % (T1 + 6);
            int h = h0 + r, w = w0 + col;
            tile[c][r][col] = (h < H_ && w < W_)
                ? img[((size_t)(b * C_ + c) * H_ + h) * W_ + w] : 0.f;
        }
    __syncthreads();

    const float* wbase = rnorm + (size_t)b * DF * NPROJ;

    float acc[4][NPROJ];
#pragma unroll
    for (int q = 0; q < 4; q++)
#pragma unroll
        for (int p = 0; p < NPROJ; p++) acc[q][p] = 0.f;

    for (int c = 0; c < C_; c++)
        for (int i = 0; i < 7; i++)
#pragma unroll
            for (int j = 0; j < 7; j++) {
                const float* wrow = wbase + (c * 49 + i * 7 + j) * NPROJ; // uniform
                float wv[NPROJ];
#pragma unroll
                for (int p = 0; p < NPROJ; p++) wv[p] = wrow[p];          // s_load
                float pix0 = tile[c][ty + i][tx + j];
                float pix1 = tile[c][ty + 8 + i][tx + j];
                float pix2 = tile[c][ty + 16 + i][tx + j];
                float pix3 = tile[c][ty + 24 + i][tx + j];
#pragma unroll
                for (int p = 0; p < NPROJ; p++) {
                    acc[0][p] = fmaf(pix0, wv[p], acc[0][p]);
                    acc[1][p] = fmaf(pix1, wv[p], acc[1][p]);
                    acc[2][p] = fmaf(pix2, wv[p], acc[2][p]);
                    acc[3][p] = fmaf(pix3, wv[p], acc[3][p]);
                }
            }

    int wo = w0 + tx;
    bool vm[4];
    int ho[4];
#pragma unroll
    for (int q = 0; q < 4; q++) {
        ho[q] = h0 + ty + 8 * q;
        vm[q] = (ho[q] < HO) && (wo < HO);
        if (vm[q]) {
            size_t n = (size_t)ho[q] * HO + wo;
#pragma unroll
            for (int p = 0; p < NPROJ; p++)
                proj[((size_t)(b * NPROJ + p)) * NPAT + n] = acc[q][p];
        }
    }

    float pmn[NPROJ], pmx[NPROJ];
#pragma unroll
    for (int p = 0; p < NPROJ; p++) {
        float mn = INFINITY, mx = -INFINITY;
#pragma unroll
        for (int q = 0; q < 4; q++) {
            if (vm[q]) {
                mn = fminf(mn, acc[q][p]);
                mx = fmaxf(mx, acc[q][p]);
            }
        }
        pmn[p] = mn; pmx[p] = mx;
    }
#pragma unroll
    for (int o = 1; o < 64; o <<= 1) {
#pragma unroll
        for (int p = 0; p < NPROJ; p++) {
            pmn[p] = fminf(pmn[p], __shfl_xor(pmn[p], o));
            pmx[p] = fmaxf(pmx[p], __shfl_xor(pmx[p], o));
        }
    }
    int wv4 = tid >> 6;
    if ((tid & 63) == 0) {
#pragma unroll
        for (int p = 0; p < NPROJ; p++) { red_mn[wv4][p] = pmn[p]; red_mx[wv4][p] = pmx[p]; }
    }
    __syncthreads();
    if (tid < NPROJ) {
        float mn = fminf(fminf(red_mn[0][tid], red_mn[1][tid]),
                         fminf(red_mn[2][tid], red_mn[3][tid]));
        float mx = fmaxf(fmaxf(red_mx[0][tid], red_mx[1][tid]),
                         fmaxf(red_mx[2][tid], red_mx[3][tid]));
        atomicMin(&keys[2 * (b * NPROJ + tid)], f2key(mn));
        atomicMax(&keys[2 * (b * NPROJ + tid) + 1], f2key(mx));
    }
}

// ---------- K2: y-hist scatter -> LDS bitmap, one atomicOr flush -------------
__global__ __launch_bounds__(256) void k_scatter(const float* __restrict__ py,
                                                 const unsigned* __restrict__ keys,
                                                 unsigned* __restrict__ bitmap) {
    __shared__ unsigned lbm[BMW];
    int bp = blockIdx.y;
    int tid = threadIdx.x;
    for (int i = tid; i < BMW; i += 256) lbm[i] = 0u;
    __syncthreads();

    float mn = key2f(keys[2 * bp]);
    float sc = key2f(keys[2 * bp + 1]) - mn;
    const float4* src = (const float4*)(py + (size_t)bp * NPAT);
    const int n4 = NPAT / 4;
    for (int i = blockIdx.x * blockDim.x + tid; i < n4;
         i += gridDim.x * blockDim.x) {
        float4 v = src[i];
        float vv[4] = { v.x, v.y, v.z, v.w };
#pragma unroll
        for (int j = 0; j < 4; j++) {
            int idx = (int)floorf(65535.f * (vv[j] - mn) / sc);
            int bit = 8 + min(max(idx, 0), 65535);
            atomicOr(&lbm[bit >> 5], 1u << (bit & 31));
        }
    }
    __syncthreads();
    unsigned* dst = bitmap + (size_t)bp * BMW;
    for (int i = tid; i < BMW; i += 256) {
        unsigned w = lbm[i];
        if (w) atomicOr(&dst[i], w);
    }
}

// ---------- K3: gather via LDS-staged bitmap + 256-entry LDS LUT -------------
__global__ __launch_bounds__(256) void k_gather(const float* __restrict__ px,
                                                const unsigned* __restrict__ keys,
                                                const unsigned* __restrict__ bitmap,
                                                float* __restrict__ out) {
    __shared__ unsigned lbm[BMW];
    __shared__ float2 lut[256];
    __shared__ float sred[4];
    int bp = blockIdx.y;
    int tid = threadIdx.x;

    const unsigned* gbm = bitmap + (size_t)bp * BMW;
    for (int i = tid; i < BMW; i += 256) lbm[i] = gbm[i];

    float g[7];
#pragma unroll
    for (int k = 0; k < 7; k++) {
        float d = (float)(k - 3);
        g[k] = expf(-(d * d) / 1.44f);   // exp((x)^2/(-2*1.2^2))**2
    }
    {
        int m = tid;   // 256 threads -> one LUT entry each
        float f[8];
#pragma unroll
        for (int k = 0; k < 8; k++) f[k] = (float)((m >> k) & 1);
        float s0 = g[0] * f[0] + g[1] * f[1] + g[2] * f[2] + g[3] * f[3]
                 + g[4] * f[4] + g[5] * f[5] + g[6] * f[6];
        float s1 = g[0] * f[1] + g[1] * f[2] + g[2] * f[3] + g[3] * f[4]
                 + g[4] * f[5] + g[5] * f[6] + g[6] * f[7];
        lut[m] = make_float2(fminf(s0, 1.f), fminf(s1, 1.f));
    }
    __syncthreads();

    float mn = key2f(keys[2 * bp]);
    float sc = key2f(keys[2 * bp + 1]) - mn;
    const float4* src = (const float4*)(px + (size_t)bp * NPAT);

    float acc = 0.f;
    const int n4 = NPAT / 4;
    for (int i = blockIdx.x * blockDim.x + tid; i < n4;
         i += gridDim.x * blockDim.x) {
        float4 v4 = src[i];
        float vv[4] = { v4.x, v4.y, v4.z, v4.w };
#pragma unroll
        for (int j = 0; j < 4; j++) {
            float v = vv[j];
            float t = (v - mn) / sc;             // in [0,1]
            float ix = t * (float)WD - 0.5f;
            float x0 = floorf(ix);
            float w1 = ix - x0;
            int x0i = (int)x0;                   // [-1, WD-1]
            int bit0 = 8 + x0i;                  // [7, 65536]
            int w = bit0 >> 5, s = bit0 & 31;
            uint64_t d = (uint64_t)lbm[w] | ((uint64_t)lbm[w + 1] << 32);
            uint32_t w8 = (uint32_t)(d >> s) & 0xFFu;
            float2 sv = lut[w8];
            float r0 = (x0i >= 0) ? sv.x : 0.f;
            float r1 = (x0i + 1 < WD) ? sv.y : 0.f;
            acc += r0 * (1.f - w1) + r1 * w1;
        }
    }
    for (int o = 32; o > 0; o >>= 1) acc += __shfl_down(acc, o);
    int wv4 = tid >> 6;
    if ((tid & 63) == 0) sred[wv4] = acc;
    __syncthreads();
    if (tid == 0) {
        float t = sred[0] + sred[1] + sred[2] + sred[3];
        atomicAdd(out, -t * (1.0f / 32.0f));
    }
}

extern "C" void kernel_launch(void* const* d_in, const int* in_sizes, int n_in,
                              void* d_out, int out_size, void* d_ws, size_t ws_size,
                              hipStream_t stream) {
    (void)in_sizes; (void)n_in; (void)out_size; (void)ws_size;
    const float* x = (const float*)d_in[0];
    const float* y = (const float*)d_in[1];
    const float* rnd = (const float*)d_in[2];
    float* out = (float*)d_out;

    float* ws = (float*)d_ws;
    float* rnorm = ws;                                     // 4704 floats
    float* px = rnorm + (size_t)B_ * DF * NPROJ;           // BP*NPAT floats
    float* py = px + (size_t)BP * NPAT;                    // BP*NPAT floats
    unsigned* keys = (unsigned*)(py + (size_t)BP * NPAT);  // 2*BP
    unsigned* bitmap = keys + 2 * BP;                      // BP*BMW u32 (263 KB)

    k_rnorm<<<BP, 64, 0, stream>>>(rnd, rnorm, keys, out);
    hipMemsetAsync(bitmap, 0, (size_t)BP * BMW * sizeof(unsigned), stream);

    dim3 g1(384 / T1, 384 / T1, 2 * B_);                   // (12,12,4)
    k_projmm<<<g1, 256, 0, stream>>>(x, y, rnorm, px, py, keys);

    k_scatter<<<dim3(8, BP), 256, 0, stream>>>(py, keys, bitmap);
    k_gather<<<dim3(70, BP), 256, 0, stream>>>(px, keys, bitmap, out);
}

// Round 12
// 108.620 us; speedup vs baseline: 1.5329x; 1.0678x over previous
//
#include <hip/hip_runtime.h>
#include <math.h>
#include <stdint.h>

#define NPROJ 16
#define NBINS 65536
#define WD (NBINS - 6)
#define BMW 2056              // bitmap u32 words per bp (8224 B); bit k = old byte k
#define B_ 2
#define C_ 3
#define H_ 384
#define W_ 384
#define HO 378
#define NPAT (HO * HO)        // 142884 (div by 4)
#define DF 147                // 3*7*7
#define BP 32                 // B_*NPROJ
#define TSTR 24               // LDS tile row stride -> uniform 2-way (free)

__device__ inline unsigned f2key(float f) {
    unsigned u = __float_as_uint(f);
    return (u & 0x80000000u) ? ~u : (u | 0x80000000u);
}
__device__ inline float key2f(unsigned k) {
    unsigned u = (k & 0x80000000u) ? (k ^ 0x80000000u) : ~k;
    return __uint_as_float(u);
}

// ---------- K0: rand/std (ddof=1); init keys; zero out + bitmap --------------
__global__ __launch_bounds__(64) void k_rnorm(const float* __restrict__ rnd,
                                              float* __restrict__ rnorm,
                                              unsigned* __restrict__ keys,
                                              unsigned* __restrict__ bitmap,
                                              float* __restrict__ out) {
    int bp = blockIdx.x;
    int b = bp / NPROJ, p = bp % NPROJ;
    int lane = threadIdx.x;
    if (lane == 0) {
        keys[2 * bp] = 0xFFFFFFFFu;
        keys[2 * bp + 1] = 0u;
        if (bp == 0) out[0] = 0.f;     // accumulated atomically in k_gather
    }
    // zero the bitmap (replaces hipMemsetAsync); re-done every call
    for (int i = bp * 64 + lane; i < BP * BMW; i += BP * 64)
        bitmap[i] = 0u;

    float s = 0.f, s2 = 0.f;
    for (int d = lane; d < DF; d += 64) {
        float v = rnd[((size_t)b * DF + d) * NPROJ + p];
        s += v; s2 += v * v;
    }
    for (int o = 32; o > 0; o >>= 1) { s += __shfl_down(s, o); s2 += __shfl_down(s2, o); }
    s = __shfl(s, 0); s2 = __shfl(s2, 0);
    float mean = s / (float)DF;
    float var = (s2 - (float)DF * mean * mean) / (float)(DF - 1);
    float inv = 1.0f / sqrtf(var);
    for (int d = lane; d < DF; d += 64) {
        size_t idx = ((size_t)b * DF + d) * NPROJ + p;
        rnorm[idx] = rnd[idx] * inv;
    }
}

// ---------- K1: proj both images; store px AND py; min/max atomics -----------
// R8 geometry (best measured): tile 32(h)x16(w), 256 threads, 2 outputs/thread,
// grid (24,12,4): z=b*2+isy. Weights via wave-uniform s_load (SGPR operands).
#define T1H 32
#define T1W 16
__global__ __launch_bounds__(256) void k_projmm(const float* __restrict__ ximg,
                                                const float* __restrict__ yimg,
                                                const float* __restrict__ rnorm,
                                                float* __restrict__ px,
                                                float* __restrict__ py,
                                                unsigned* __restrict__ keys) {
    __shared__ float tile[C_][T1H + 6][TSTR];   // [3][38][24]
    __shared__ float red_mn[4][NPROJ], red_mx[4][NPROJ];
    int bz = blockIdx.z;
    int b = bz >> 1, isy = bz & 1;
    const float* img = isy ? yimg : ximg;
    float* proj = isy ? py : px;
    int tid = threadIdx.x;
    int tx = tid & 15, ty = tid >> 4;              // 16x16 threads, rows 16 apart
    int h0 = blockIdx.y * T1H, w0 = blockIdx.x * T1W;

    for (int c = 0; c < C_; c++)
        for (int i = tid; i < (T1H + 6) * (T1W + 6); i += 256) {
            int r = i / (T1W + 6), col = i % (T1W + 6);
            int h = h0 + r, w = w0 + col;
            tile[c][r][col] = (h < H_ && w < W_)
                ? img[((size_t)(b * C_ + c) * H_ + h) * W_ + w] : 0.f;
        }
    __syncthreads();

    const float* wbase = rnorm + (size_t)b * DF * NPROJ;

    float acc[2][NPROJ];
#pragma unroll
    for (int q = 0; q < 2; q++)
#pragma unroll
        for (int p = 0; p < NPROJ; p++) acc[q][p] = 0.f;

    for (int c = 0; c < C_; c++)
        for (int i = 0; i < 7; i++)
#pragma unroll
            for (int j = 0; j < 7; j++) {
                const float* wrow = wbase + (c * 49 + i * 7 + j) * NPROJ; // uniform
                float wv[NPROJ];
#pragma unroll
                for (int p = 0; p < NPROJ; p++) wv[p] = wrow[p];          // s_load
                float pix0 = tile[c][ty + i][tx + j];
                float pix1 = tile[c][ty + 16 + i][tx + j];
#pragma unroll
                for (int p = 0; p < NPROJ; p++) {
                    acc[0][p] = fmaf(pix0, wv[p], acc[0][p]);
                    acc[1][p] = fmaf(pix1, wv[p], acc[1][p]);
                }
            }

    int wo = w0 + tx;
    int ho0 = h0 + ty, ho1 = h0 + ty + 16;
    bool vm0 = (ho0 < HO) && (wo < HO);
    bool vm1 = (ho1 < HO) && (wo < HO);

    if (vm0) {
        size_t n = (size_t)ho0 * HO + wo;
#pragma unroll
        for (int p = 0; p < NPROJ; p++)
            proj[((size_t)(b * NPROJ + p)) * NPAT + n] = acc[0][p];
    }
    if (vm1) {
        size_t n = (size_t)ho1 * HO + wo;
#pragma unroll
        for (int p = 0; p < NPROJ; p++)
            proj[((size_t)(b * NPROJ + p)) * NPAT + n] = acc[1][p];
    }

    float pmn[NPROJ], pmx[NPROJ];
#pragma unroll
    for (int p = 0; p < NPROJ; p++) {
        float mn = INFINITY, mx = -INFINITY;
        if (vm0) { mn = acc[0][p]; mx = acc[0][p]; }
        if (vm1) { mn = fminf(mn, acc[1][p]); mx = fmaxf(mx, acc[1][p]); }
        pmn[p] = mn; pmx[p] = mx;
    }
#pragma unroll
    for (int o = 1; o < 64; o <<= 1) {
#pragma unroll
        for (int p = 0; p < NPROJ; p++) {
            pmn[p] = fminf(pmn[p], __shfl_xor(pmn[p], o));
            pmx[p] = fmaxf(pmx[p], __shfl_xor(pmx[p], o));
        }
    }
    int wv4 = tid >> 6;
    if ((tid & 63) == 0) {
#pragma unroll
        for (int p = 0; p < NPROJ; p++) { red_mn[wv4][p] = pmn[p]; red_mx[wv4][p] = pmx[p]; }
    }
    __syncthreads();
    if (tid < NPROJ) {
        float mn = fminf(fminf(red_mn[0][tid], red_mn[1][tid]),
                         fminf(red_mn[2][tid], red_mn[3][tid]));
        float mx = fmaxf(fmaxf(red_mx[0][tid], red_mx[1][tid]),
                         fmaxf(red_mx[2][tid], red_mx[3][tid]));
        atomicMin(&keys[2 * (b * NPROJ + tid)], f2key(mn));
        atomicMax(&keys[2 * (b * NPROJ + tid) + 1], f2key(mx));
    }
}

// ---------- K2: y-hist scatter -> LDS bitmap, one atomicOr flush -------------
__global__ __launch_bounds__(256) void k_scatter(const float* __restrict__ py,
                                                 const unsigned* __restrict__ keys,
                                                 unsigned* __restrict__ bitmap) {
    __shared__ unsigned lbm[BMW];
    int bp = blockIdx.y;
    int tid = threadIdx.x;
    for (int i = tid; i < BMW; i += 256) lbm[i] = 0u;
    __syncthreads();

    float mn = key2f(keys[2 * bp]);
    float sc = key2f(keys[2 * bp + 1]) - mn;
    const float4* src = (const float4*)(py + (size_t)bp * NPAT);
    const int n4 = NPAT / 4;
    for (int i = blockIdx.x * blockDim.x + tid; i < n4;
         i += gridDim.x * blockDim.x) {
        float4 v = src[i];
        float vv[4] = { v.x, v.y, v.z, v.w };
#pragma unroll
        for (int j = 0; j < 4; j++) {
            int idx = (int)floorf(65535.f * (vv[j] - mn) / sc);
            int bit = 8 + min(max(idx, 0), 65535);
            atomicOr(&lbm[bit >> 5], 1u << (bit & 31));
        }
    }
    __syncthreads();
    unsigned* dst = bitmap + (size_t)bp * BMW;
    for (int i = tid; i < BMW; i += 256) {
        unsigned w = lbm[i];
        if (w) atomicOr(&dst[i], w);
    }
}

// ---------- K3: gather via LDS-staged bitmap + 256-entry LDS LUT -------------
__global__ __launch_bounds__(256) void k_gather(const float* __restrict__ px,
                                                const unsigned* __restrict__ keys,
                                                const unsigned* __restrict__ bitmap,
                                                float* __restrict__ out) {
    __shared__ unsigned lbm[BMW];
    __shared__ float2 lut[256];
    __shared__ float sred[4];
    int bp = blockIdx.y;
    int tid = threadIdx.x;

    const unsigned* gbm = bitmap + (size_t)bp * BMW;
    for (int i = tid; i < BMW; i += 256) lbm[i] = gbm[i];

    float g[7];
#pragma unroll
    for (int k = 0; k < 7; k++) {
        float d = (float)(k - 3);
        g[k] = expf(-(d * d) / 1.44f);   // exp((x)^2/(-2*1.2^2))**2
    }
    {
        int m = tid;   // 256 threads -> one LUT entry each
        float f[8];
#pragma unroll
        for (int k = 0; k < 8; k++) f[k] = (float)((m >> k) & 1);
        float s0 = g[0] * f[0] + g[1] * f[1] + g[2] * f[2] + g[3] * f[3]
                 + g[4] * f[4] + g[5] * f[5] + g[6] * f[6];
        float s1 = g[0] * f[1] + g[1] * f[2] + g[2] * f[3] + g[3] * f[4]
                 + g[4] * f[5] + g[5] * f[6] + g[6] * f[7];
        lut[m] = make_float2(fminf(s0, 1.f), fminf(s1, 1.f));
    }
    __syncthreads();

    float mn = key2f(keys[2 * bp]);
    float sc = key2f(keys[2 * bp + 1]) - mn;
    const float4* src = (const float4*)(px + (size_t)bp * NPAT);

    float acc = 0.f;
    const int n4 = NPAT / 4;
    for (int i = blockIdx.x * blockDim.x + tid; i < n4;
         i += gridDim.x * blockDim.x) {
        float4 v4 = src[i];
        float vv[4] = { v4.x, v4.y, v4.z, v4.w };
#pragma unroll
        for (int j = 0; j < 4; j++) {
            float v = vv[j];
            float t = (v - mn) / sc;             // in [0,1]
            float ix = t * (float)WD - 0.5f;
            float x0 = floorf(ix);
            float w1 = ix - x0;
            int x0i = (int)x0;                   // [-1, WD-1]
            int bit0 = 8 + x0i;                  // [7, 65536]
            int w = bit0 >> 5, s = bit0 & 31;
            uint64_t d = (uint64_t)lbm[w] | ((uint64_t)lbm[w + 1] << 32);
            uint32_t w8 = (uint32_t)(d >> s) & 0xFFu;
            float2 sv = lut[w8];
            float r0 = (x0i >= 0) ? sv.x : 0.f;
            float r1 = (x0i + 1 < WD) ? sv.y : 0.f;
            acc += r0 * (1.f - w1) + r1 * w1;
        }
    }
    for (int o = 32; o > 0; o >>= 1) acc += __shfl_down(acc, o);
    int wv4 = tid >> 6;
    if ((tid & 63) == 0) sred[wv4] = acc;
    __syncthreads();
    if (tid == 0) {
        float t = sred[0] + sred[1] + sred[2] + sred[3];
        atomicAdd(out, -t * (1.0f / 32.0f));
    }
}

extern "C" void kernel_launch(void* const* d_in, const int* in_sizes, int n_in,
                              void* d_out, int out_size, void* d_ws, size_t ws_size,
                              hipStream_t stream) {
    (void)in_sizes; (void)n_in; (void)out_size; (void)ws_size;
    const float* x = (const float*)d_in[0];
    const float* y = (const float*)d_in[1];
    const float* rnd = (const float*)d_in[2];
    float* out = (float*)d_out;

    float* ws = (float*)d_ws;
    float* rnorm = ws;                                     // 4704 floats
    float* px = rnorm + (size_t)B_ * DF * NPROJ;           // BP*NPAT floats
    float* py = px + (size_t)BP * NPAT;                    // BP*NPAT floats
    unsigned* keys = (unsigned*)(py + (size_t)BP * NPAT);  // 2*BP
    unsigned* bitmap = keys + 2 * BP;                      // BP*BMW u32 (263 KB)

    k_rnorm<<<BP, 64, 0, stream>>>(rnd, rnorm, keys, bitmap, out);

    dim3 g1(384 / T1W, 384 / T1H, 2 * B_);                 // (24,12,4)
    k_projmm<<<g1, 256, 0, stream>>>(x, y, rnorm, px, py, keys);

    k_scatter<<<dim3(8, BP), 256, 0, stream>>>(py, keys, bitmap);
    k_gather<<<dim3(70, BP), 256, 0, stream>>>(px, keys, bitmap, out);
}